// Round 1
// baseline (3138.367 us; speedup 1.0000x reference)
//
#include <hip/hip_runtime.h>
#include <hip/hip_bf16.h>
#include <math.h>

// Model constants (fixed by the reference problem)
#define DMODEL 1280
#define NHEADS 16
#define HDIM   80
#define FDIM   5120
#define NLAYER 4
#define GPOS   48
#define SEGLEN 512

typedef __attribute__((ext_vector_type(8))) short bf16x8;
typedef __attribute__((ext_vector_type(4))) float f32x4;

__device__ __forceinline__ unsigned short f2bf(float f) {
  unsigned int u = __float_as_uint(f);
  u = (u + 0x7FFFu + ((u >> 16) & 1u)) >> 16;  // RNE
  return (unsigned short)u;
}

__device__ __forceinline__ float gelu_tanh(float x) {
  float x3 = x * x * x;
  return 0.5f * x * (1.f + tanhf(0.7978845608028654f * (x + 0.044715f * x3)));
}

// ---------------------------------------------------------------------------
// Generic 128x128-tile bf16 MFMA GEMM: C = act(scale*A.B + bias) [+ res]
// A: M x K row-major fp32. B: if BT==0, K x N row-major (weights); if BT==1,
// N x K row-major (second operand pre-transposed, e.g. K for Q.K^T).
// Batched via blockIdx.z with element strides sA/sB/sC (res unbatched).
// Requires M%128==0, N%128==0, K%32==0, lda/ldb%4==0.
// ---------------------------------------------------------------------------
template <int BT, int ACT, int RES>
__global__ __launch_bounds__(256) void gemm_k(
    const float* __restrict__ A, const float* __restrict__ B,
    const float* __restrict__ bias, const float* __restrict__ res,
    float* __restrict__ C, int M, int Nn, int Kd, int lda, int ldb, int ldc,
    float scale, long long sA, long long sB, long long sC) {
  // stride 40 ushorts (80 B = 20 words): spreads banks, keeps 16B alignment
  __shared__ __align__(16) unsigned short Al[128][40];
  __shared__ __align__(16) unsigned short Bl[128][40];
  const int bz = blockIdx.z;
  const float* Ab = A + (long long)bz * sA;
  const float* Bb = B + (long long)bz * sB;
  float* Cb = C + (long long)bz * sC;
  const int n0 = blockIdx.x * 128;
  const int m0 = blockIdx.y * 128;
  const int t = threadIdx.x;
  const int lane = t & 63;
  const int wv = t >> 6;          // 4 waves
  const int wr = wv >> 1;         // wave row quadrant (64 rows)
  const int wc = wv & 1;          // wave col quadrant (64 cols)
  const int m16 = lane & 15;
  const int q = lane >> 4;        // 0..3

  f32x4 acc[4][4];
#pragma unroll
  for (int i = 0; i < 4; i++)
#pragma unroll
    for (int j = 0; j < 4; j++)
#pragma unroll
      for (int r = 0; r < 4; r++) acc[i][j][r] = 0.f;

  for (int k0 = 0; k0 < Kd; k0 += 32) {
    // --- stage A tile 128x32 (row-major in LDS) ---
#pragma unroll
    for (int i = 0; i < 4; i++) {
      int idx = t + 256 * i;       // 1024 float4 total
      int r = idx >> 3;
      int c4 = (idx & 7) * 4;
      float4 v = *(const float4*)(Ab + (long long)(m0 + r) * lda + (k0 + c4));
      ushort4 hx;
      hx.x = f2bf(v.x); hx.y = f2bf(v.y); hx.z = f2bf(v.z); hx.w = f2bf(v.w);
      *(ushort4*)&Al[r][c4] = hx;
    }
    // --- stage B tile into Bl[n][k] ---
    if (BT) {
#pragma unroll
      for (int i = 0; i < 4; i++) {
        int idx = t + 256 * i;
        int r = idx >> 3;
        int c4 = (idx & 7) * 4;
        float4 v = *(const float4*)(Bb + (long long)(n0 + r) * ldb + (k0 + c4));
        ushort4 hx;
        hx.x = f2bf(v.x); hx.y = f2bf(v.y); hx.z = f2bf(v.z); hx.w = f2bf(v.w);
        *(ushort4*)&Bl[r][c4] = hx;
      }
    } else {
      int n = t & 127;
      int kc = (t >> 7) * 16;
      unsigned short tmp[16];
#pragma unroll
      for (int i = 0; i < 16; i++)
        tmp[i] = f2bf(Bb[(long long)(k0 + kc + i) * ldb + (n0 + n)]);
#pragma unroll
      for (int i = 0; i < 4; i++) {
        ushort4 hx;
        hx.x = tmp[4 * i]; hx.y = tmp[4 * i + 1];
        hx.z = tmp[4 * i + 2]; hx.w = tmp[4 * i + 3];
        *(ushort4*)&Bl[n][kc + 4 * i] = hx;
      }
    }
    __syncthreads();
    // --- fragments + 16 MFMAs per wave ---
    bf16x8 av[4], bv[4];
#pragma unroll
    for (int mi = 0; mi < 4; mi++)
      av[mi] = *(const bf16x8*)&Al[wr * 64 + mi * 16 + m16][q * 8];
#pragma unroll
    for (int ni = 0; ni < 4; ni++)
      bv[ni] = *(const bf16x8*)&Bl[wc * 64 + ni * 16 + m16][q * 8];
#pragma unroll
    for (int mi = 0; mi < 4; mi++)
#pragma unroll
      for (int ni = 0; ni < 4; ni++)
        acc[mi][ni] = __builtin_amdgcn_mfma_f32_16x16x32_bf16(
            av[mi], bv[ni], acc[mi][ni], 0, 0, 0);
    __syncthreads();
  }
  // --- epilogue: D layout col=lane&15, row=(lane>>4)*4+r ---
#pragma unroll
  for (int mi = 0; mi < 4; mi++) {
#pragma unroll
    for (int r = 0; r < 4; r++) {
      int row = m0 + wr * 64 + mi * 16 + q * 4 + r;
#pragma unroll
      for (int ni = 0; ni < 4; ni++) {
        int col = n0 + wc * 64 + ni * 16 + m16;
        float v = acc[mi][ni][r] * scale;
        if (bias) v += bias[col];
        if (ACT) v = gelu_tanh(v);
        if (RES) v += res[(long long)row * ldc + col];
        Cb[(long long)row * ldc + col] = v;
      }
    }
  }
}

// ---------------------------------------------------------------------------
// Token coordinates (row/col/h/w per token) from grid_thw
// ---------------------------------------------------------------------------
__global__ void coords_k(const int* __restrict__ g, int nimg,
                         int* __restrict__ rw, int* __restrict__ cl,
                         int* __restrict__ hh, int* __restrict__ ww, int N) {
  int t = blockIdx.x * 256 + threadIdx.x;
  if (t >= N) return;
  int c = 0, local = 0, H = 1, W = 1;
  for (int i = 0; i < nimg; i++) {
    int tpi = g[i * 3] * g[i * 3 + 1] * g[i * 3 + 2];
    if (t >= c && t < c + tpi) { local = t - c; H = g[i * 3 + 1]; W = g[i * 3 + 2]; }
    c += tpi;
  }
  int hw = H * W;
  int sp = local % hw;
  int mw = W >> 1;                 // merge_size = 2
  int gr = sp >> 2, intra = sp & 3;
  rw[t] = (gr / mw) * 2 + (intra >> 1);
  cl[t] = (gr % mw) * 2 + (intra & 1);
  hh[t] = H; ww[t] = W;
}

// ---------------------------------------------------------------------------
// x += bilinear(pos_embed)  (one block per token, 320 threads x float4)
// ---------------------------------------------------------------------------
__global__ void peadd_k(float* __restrict__ x, const float* __restrict__ pe,
                        const int* __restrict__ rw, const int* __restrict__ cl,
                        const int* __restrict__ hh, const int* __restrict__ ww) {
  int n = blockIdx.x;
  int d = threadIdx.x * 4;
  int H = hh[n], W = ww[n];
  float rf = (H > 1) ? (float)rw[n] * (float)(GPOS - 1) / (float)(H - 1) : 0.f;
  float cf = (W > 1) ? (float)cl[n] * (float)(GPOS - 1) / (float)(W - 1) : 0.f;
  int r0 = (int)floorf(rf), c0 = (int)floorf(cf);
  int r1 = min(r0 + 1, GPOS - 1), c1 = min(c0 + 1, GPOS - 1);
  float wr = rf - (float)r0, wc = cf - (float)c0;
  float w00 = (1.f - wr) * (1.f - wc), w01 = (1.f - wr) * wc;
  float w10 = wr * (1.f - wc), w11 = wr * wc;
  float4 v00 = *(const float4*)(pe + (long long)(r0 * GPOS + c0) * DMODEL + d);
  float4 v01 = *(const float4*)(pe + (long long)(r0 * GPOS + c1) * DMODEL + d);
  float4 v10 = *(const float4*)(pe + (long long)(r1 * GPOS + c0) * DMODEL + d);
  float4 v11 = *(const float4*)(pe + (long long)(r1 * GPOS + c1) * DMODEL + d);
  float4 xv = *(float4*)(x + (long long)n * DMODEL + d);
  xv.x += w00 * v00.x + w01 * v01.x + w10 * v10.x + w11 * v11.x;
  xv.y += w00 * v00.y + w01 * v01.y + w10 * v10.y + w11 * v11.y;
  xv.z += w00 * v00.z + w01 * v01.z + w10 * v10.z + w11 * v11.z;
  xv.w += w00 * v00.w + w01 * v01.w + w10 * v10.w + w11 * v11.w;
  *(float4*)(x + (long long)n * DMODEL + d) = xv;
}

// ---------------------------------------------------------------------------
// LayerNorm over D=1280 (one block of 320 threads per row)
// ---------------------------------------------------------------------------
__global__ void ln_k(const float* __restrict__ X, float* __restrict__ Y,
                     const float* __restrict__ s, const float* __restrict__ b) {
  int row = blockIdx.x;
  int d = threadIdx.x * 4;
  const float* x = X + (long long)row * DMODEL;
  float4 v = *(const float4*)(x + d);
  float sum = v.x + v.y + v.z + v.w;
#pragma unroll
  for (int o = 32; o; o >>= 1) sum += __shfl_xor(sum, o);
  __shared__ float red[8];
  int wv = threadIdx.x >> 6, ln = threadIdx.x & 63;
  if (ln == 0) red[wv] = sum;
  __syncthreads();
  float mu = 0.f;
  for (int i = 0; i < 5; i++) mu += red[i];
  mu *= (1.f / DMODEL);
  float dx = v.x - mu, dy = v.y - mu, dz = v.z - mu, dw = v.w - mu;
  float s2 = dx * dx + dy * dy + dz * dz + dw * dw;
#pragma unroll
  for (int o = 32; o; o >>= 1) s2 += __shfl_xor(s2, o);
  __syncthreads();
  if (ln == 0) red[wv] = s2;
  __syncthreads();
  float var = 0.f;
  for (int i = 0; i < 5; i++) var += red[i];
  var *= (1.f / DMODEL);
  float rs = rsqrtf(var + 1e-6f);
  float4 o4;
  o4.x = dx * rs * s[d] + b[d];
  o4.y = dy * rs * s[d + 1] + b[d + 1];
  o4.z = dz * rs * s[d + 2] + b[d + 2];
  o4.w = dw * rs * s[d + 3] + b[d + 3];
  *(float4*)(Y + (long long)row * DMODEL + d) = o4;
}

// ---------------------------------------------------------------------------
// RoPE + head-major repack: qkv[n][3][h][80] -> qr/kr [h][n][96] (zero-padded),
// v -> vp [h][n][128] (zero-padded). grid (N, 16), 64 threads.
// ---------------------------------------------------------------------------
__global__ void rope_k(const float* __restrict__ qkv, const int* __restrict__ rw,
                       const int* __restrict__ cl, float* __restrict__ qr,
                       float* __restrict__ kr, float* __restrict__ vp, int N) {
  int n = blockIdx.x, h = blockIdx.y, t = threadIdx.x;
  const float* src = qkv + (long long)n * (3 * DMODEL) + h * HDIM;
  long long ob96 = ((long long)h * N + n) * 96;
  long long ob128 = ((long long)h * N + n) * 128;
  if (t < 40) {
    float pos = (t < 20) ? (float)rw[n] : (float)cl[n];
    float infr = exp2f(-13.287712379549449f * (float)(t % 20) * (1.f / 20.f));
    float f = pos * infr;
    float cs = cosf(f), sn = sinf(f);
    float q0 = src[t], q1 = src[t + 40];
    qr[ob96 + t] = q0 * cs - q1 * sn;
    qr[ob96 + t + 40] = q1 * cs + q0 * sn;
    float k0 = src[DMODEL + t], k1 = src[DMODEL + t + 40];
    kr[ob96 + t] = k0 * cs - k1 * sn;
    kr[ob96 + t + 40] = k1 * cs + k0 * sn;
    vp[ob128 + t] = src[2 * DMODEL + t];
    vp[ob128 + t + 40] = src[2 * DMODEL + t + 40];
  } else {
    int u = t - 40;  // 0..23
    if (u < 16) { qr[ob96 + 80 + u] = 0.f; kr[ob96 + 80 + u] = 0.f; }
    vp[ob128 + 80 + u] = 0.f;
    vp[ob128 + 104 + u] = 0.f;
  }
}

// ---------------------------------------------------------------------------
// Row softmax over 512 (one wave per row); in-segment mask is all-true.
// ---------------------------------------------------------------------------
__global__ void softmax_k(float* __restrict__ sc) {
  long long base = ((long long)blockIdx.y * SEGLEN + blockIdx.x) * SEGLEN;
  float* p = sc + base;
  int t = threadIdx.x;
  float4 a = *(float4*)(p + t * 4);
  float4 b = *(float4*)(p + 256 + t * 4);
  float mx = fmaxf(fmaxf(fmaxf(a.x, a.y), fmaxf(a.z, a.w)),
                   fmaxf(fmaxf(b.x, b.y), fmaxf(b.z, b.w)));
#pragma unroll
  for (int o = 32; o; o >>= 1) mx = fmaxf(mx, __shfl_xor(mx, o));
  a.x = __expf(a.x - mx); a.y = __expf(a.y - mx);
  a.z = __expf(a.z - mx); a.w = __expf(a.w - mx);
  b.x = __expf(b.x - mx); b.y = __expf(b.y - mx);
  b.z = __expf(b.z - mx); b.w = __expf(b.w - mx);
  float sm = a.x + a.y + a.z + a.w + b.x + b.y + b.z + b.w;
#pragma unroll
  for (int o = 32; o; o >>= 1) sm += __shfl_xor(sm, o);
  float r = 1.f / sm;
  a.x *= r; a.y *= r; a.z *= r; a.w *= r;
  b.x *= r; b.y *= r; b.z *= r; b.w *= r;
  *(float4*)(p + t * 4) = a;
  *(float4*)(p + 256 + t * 4) = b;
}

// ---------------------------------------------------------------------------
// op[b=(h*4+seg)][m][128] -> o[n][h*80+k]
// ---------------------------------------------------------------------------
__global__ void repack_k(const float* __restrict__ op, float* __restrict__ o, int N) {
  int id = blockIdx.x * 256 + threadIdx.x;
  if (id >= N * DMODEL) return;
  int n = id / DMODEL, c = id % DMODEL;
  int h = c / HDIM, kk = c % HDIM;
  int seg = n >> 9, m = n & (SEGLEN - 1);
  o[id] = op[(((long long)h * 4 + seg) * SEGLEN + m) * 128 + kk];
}

// ---------------------------------------------------------------------------
static void launch_gemm(hipStream_t st, int bt, int act, int resf,
                        const float* A, const float* B, const float* bias,
                        const float* res, float* C, int M, int Nn, int Kd,
                        int lda, int ldb, int ldc, float scale, long long sA,
                        long long sB, long long sC, int batches) {
  dim3 g(Nn / 128, M / 128, batches), blk(256);
  if (bt)
    gemm_k<1, 0, 0><<<g, blk, 0, st>>>(A, B, bias, res, C, M, Nn, Kd, lda, ldb, ldc, scale, sA, sB, sC);
  else if (act)
    gemm_k<0, 1, 0><<<g, blk, 0, st>>>(A, B, bias, res, C, M, Nn, Kd, lda, ldb, ldc, scale, sA, sB, sC);
  else if (resf)
    gemm_k<0, 0, 1><<<g, blk, 0, st>>>(A, B, bias, res, C, M, Nn, Kd, lda, ldb, ldc, scale, sA, sB, sC);
  else
    gemm_k<0, 0, 0><<<g, blk, 0, st>>>(A, B, bias, res, C, M, Nn, Kd, lda, ldb, ldc, scale, sA, sB, sC);
}

extern "C" void kernel_launch(void* const* d_in, const int* in_sizes, int n_in,
                              void* d_out, int out_size, void* d_ws, size_t ws_size,
                              hipStream_t stream) {
  const float* pixels = (const float*)d_in[0];
  const int* grid_thw = (const int*)d_in[1];
  const float* pos_embed = (const float*)d_in[2];
  const float* patch_w = (const float*)d_in[3];
  const float* patch_b = (const float*)d_in[4];
  const float* ln1_s = (const float*)d_in[5];
  const float* ln1_b = (const float*)d_in[6];
  const float* qkv_w = (const float*)d_in[7];
  const float* qkv_b = (const float*)d_in[8];
  const float* proj_w = (const float*)d_in[9];
  const float* proj_b = (const float*)d_in[10];
  const float* ln2_s = (const float*)d_in[11];
  const float* ln2_b = (const float*)d_in[12];
  const float* fc1_w = (const float*)d_in[13];
  const float* fc1_b = (const float*)d_in[14];
  const float* fc2_w = (const float*)d_in[15];
  const float* fc2_b = (const float*)d_in[16];
  const float* mns = (const float*)d_in[17];
  const float* mnb = (const float*)d_in[18];
  const float* mf1w = (const float*)d_in[19];
  const float* mf1b = (const float*)d_in[20];
  const float* mf2w = (const float*)d_in[21];
  const float* mf2b = (const float*)d_in[22];
  float* out = (float*)d_out;

  const int N = in_sizes[0] / 1536;     // 2048 tokens
  const int nimg = in_sizes[1] / 3;     // 4 images
  const int nseg = N / SEGLEN;          // 4
  const int nb = NHEADS * nseg;         // 64 attention batches

  char* w = (char*)d_ws;
  size_t off = 0;
  auto alloc = [&](size_t bytes) -> void* {
    void* p = w + off;
    off += (bytes + 255) & ~(size_t)255;
    return p;
  };
  int* rw = (int*)alloc((size_t)N * 4);
  int* cl = (int*)alloc((size_t)N * 4);
  int* hh = (int*)alloc((size_t)N * 4);
  int* ww = (int*)alloc((size_t)N * 4);
  float* x = (float*)alloc((size_t)N * DMODEL * 4);
  float* hdn = (float*)alloc((size_t)N * DMODEL * 4);
  float* qkv = (float*)alloc((size_t)N * 3 * DMODEL * 4);
  float* qr = (float*)alloc((size_t)NHEADS * N * 96 * 4);
  float* kr = (float*)alloc((size_t)NHEADS * N * 96 * 4);
  float* vp = (float*)alloc((size_t)NHEADS * N * 128 * 4);
  float* sc = (float*)alloc((size_t)nb * SEGLEN * SEGLEN * 4);  // also ff
  float* op = (float*)alloc((size_t)nb * SEGLEN * 128 * 4);
  float* o = (float*)alloc((size_t)N * DMODEL * 4);
  (void)ws_size;

  const float iscale = 0.11180339887498949f;  // 80^-0.5

  // coords
  coords_k<<<dim3((N + 255) / 256), dim3(256), 0, stream>>>(grid_thw, nimg, rw, cl, hh, ww, N);
  // patch embed: x = pixels @ patch_w + patch_b
  launch_gemm(stream, 0, 0, 0, pixels, patch_w, patch_b, nullptr, x,
              N, DMODEL, 1536, 1536, DMODEL, DMODEL, 1.f, 0, 0, 0, 1);
  // x += bilinear pos embed
  peadd_k<<<dim3(N), dim3(320), 0, stream>>>(x, pos_embed, rw, cl, hh, ww);

  for (int l = 0; l < NLAYER; l++) {
    const float* qw = qkv_w + (size_t)l * DMODEL * 3 * DMODEL;
    const float* qb = qkv_b + (size_t)l * 3 * DMODEL;
    const float* pw = proj_w + (size_t)l * DMODEL * DMODEL;
    const float* pb = proj_b + (size_t)l * DMODEL;
    const float* f1w = fc1_w + (size_t)l * DMODEL * FDIM;
    const float* f1b = fc1_b + (size_t)l * FDIM;
    const float* f2w = fc2_w + (size_t)l * FDIM * DMODEL;
    const float* f2b = fc2_b + (size_t)l * DMODEL;

    // LN1
    ln_k<<<dim3(N), dim3(320), 0, stream>>>(x, hdn, ln1_s + l * DMODEL, ln1_b + l * DMODEL);
    // QKV
    launch_gemm(stream, 0, 0, 0, hdn, qw, qb, nullptr, qkv,
                N, 3 * DMODEL, DMODEL, DMODEL, 3 * DMODEL, 3 * DMODEL, 1.f, 0, 0, 0, 1);
    // RoPE + repack heads
    rope_k<<<dim3(N, NHEADS), dim3(64), 0, stream>>>(qkv, rw, cl, qr, kr, vp, N);
    // scores = scale * Q.K^T per (head,seg)
    launch_gemm(stream, 1, 0, 0, qr, kr, nullptr, nullptr, sc,
                SEGLEN, SEGLEN, 96, 96, 96, SEGLEN, iscale,
                (long long)SEGLEN * 96, (long long)SEGLEN * 96,
                (long long)SEGLEN * SEGLEN, nb);
    // softmax rows
    softmax_k<<<dim3(SEGLEN, nb), dim3(64), 0, stream>>>(sc);
    // O = P.V (N padded to 128)
    launch_gemm(stream, 0, 0, 0, sc, vp, nullptr, nullptr, op,
                SEGLEN, 128, SEGLEN, SEGLEN, 128, 128, 1.f,
                (long long)SEGLEN * SEGLEN, (long long)SEGLEN * 128,
                (long long)SEGLEN * 128, nb);
    // repack to [n][1280]
    repack_k<<<dim3((N * DMODEL + 255) / 256), dim3(256), 0, stream>>>(op, o, N);
    // x = x + o @ proj_w + proj_b
    launch_gemm(stream, 0, 0, 1, o, pw, pb, x, x,
                N, DMODEL, DMODEL, DMODEL, DMODEL, DMODEL, 1.f, 0, 0, 0, 1);
    // LN2
    ln_k<<<dim3(N), dim3(320), 0, stream>>>(x, hdn, ln2_s + l * DMODEL, ln2_b + l * DMODEL);
    // ff = gelu(hdn @ fc1 + b)   (stored in sc)
    launch_gemm(stream, 0, 1, 0, hdn, f1w, f1b, nullptr, sc,
                N, FDIM, DMODEL, DMODEL, FDIM, FDIM, 1.f, 0, 0, 0, 1);
    // x = x + ff @ fc2 + b
    launch_gemm(stream, 0, 0, 1, sc, f2w, f2b, x, x,
                N, DMODEL, FDIM, FDIM, DMODEL, DMODEL, 1.f, 0, 0, 0, 1);
  }

  // merger: normed = LN(x) viewed as (N/4, 5120)
  ln_k<<<dim3(N), dim3(320), 0, stream>>>(x, hdn, mns, mnb);
  const int Mm = N / 4;  // 512
  // ff = gelu(normed @ m_fc1 + b)  (in sc)
  launch_gemm(stream, 0, 1, 0, hdn, mf1w, mf1b, nullptr, sc,
              Mm, FDIM, FDIM, FDIM, FDIM, FDIM, 1.f, 0, 0, 0, 1);
  // out = ff @ m_fc2 + b
  launch_gemm(stream, 0, 0, 0, sc, mf2w, mf2b, nullptr, out,
              Mm, 2048, FDIM, FDIM, 2048, 2048, 1.f, 0, 0, 0, 1);
}

// Round 2
// 1826.361 us; speedup vs baseline: 1.7184x; 1.7184x over previous
//
#include <hip/hip_runtime.h>
#include <math.h>

#define DMODEL 1280
#define NHEADS 16
#define FDIM   5120
#define GPOS   48
#define SEG    512

typedef __attribute__((ext_vector_type(8))) short bf16x8;
typedef __attribute__((ext_vector_type(4))) float f32x4;
typedef unsigned short u16;

__device__ __forceinline__ u16 f2bf(float f) {
  unsigned int u = __float_as_uint(f);
  u = (u + 0x7FFFu + ((u >> 16) & 1u)) >> 16;  // RNE
  return (u16)u;
}
__device__ __forceinline__ float bf2f(u16 u) {
  return __uint_as_float((unsigned int)u << 16);
}
__device__ __forceinline__ float gelu_tanh(float x) {
  float x3 = x * x * x;
  return 0.5f * x * (1.f + tanhf(0.7978845608028654f * (x + 0.044715f * x3)));
}

typedef const __attribute__((address_space(1))) unsigned int* gas_t;
typedef __attribute__((address_space(3))) unsigned int* las_t;
__device__ __forceinline__ void async16(const void* g, void* l) {
  __builtin_amdgcn_global_load_lds((gas_t)g, (las_t)l, 16, 0, 0);
}

// ---------------------------------------------------------------------------
// m97-style bf16 GEMM. A: [M][K] bf16 row-major (lda). B: [N][K] bf16
// row-major (ldb) i.e. pre-transposed weights. 128x128 tile, 4 waves, 4x4
// MFMA 16x16x32. Staging via global_load_lds dwordx4 into unpadded LDS.
// EPI: 0 = raw fp32 partial (split-K, C[sp][M][N]); 1 = bf16 +bias;
//      2 = fp32 *scale (+bias if non-null); 3 = bf16 +bias +gelu.
// ---------------------------------------------------------------------------
template <int EPI>
__global__ __launch_bounds__(256) void gemm_bt(
    const u16* __restrict__ A, const u16* __restrict__ B,
    const float* __restrict__ bias, void* __restrict__ Cv,
    int Kd, int lda, int ldb, int ldc, float scale,
    long long sA, long long sB, long long sC, int nsplit, long long pstride) {
  __shared__ __align__(16) u16 As[128 * 32];
  __shared__ __align__(16) u16 Bs[128 * 32];
  const int bz = blockIdx.z;
  const int bat = bz / nsplit, sp = bz - bat * nsplit;
  const int Ks = Kd / nsplit;
  const u16* Ab = A + (long long)bat * sA + (long long)sp * Ks;
  const u16* Bb = B + (long long)bat * sB + (long long)sp * Ks;
  const int n0 = blockIdx.x * 128, m0 = blockIdx.y * 128;
  const int t = threadIdx.x, ln = t & 63, w = t >> 6;
  const int srow = ln >> 2, scol = (ln & 3) * 8;
  const int m16 = ln & 15, q = ln >> 4;
  const int wr = w >> 1, wc = w & 1;

  f32x4 acc[4][4];
#pragma unroll
  for (int i = 0; i < 4; i++)
#pragma unroll
    for (int j = 0; j < 4; j++)
#pragma unroll
      for (int r = 0; r < 4; r++) acc[i][j][r] = 0.f;

  for (int k0 = 0; k0 < Ks; k0 += 32) {
#pragma unroll
    for (int it = 0; it < 2; it++) {
      int ra = it * 64 + w * 16;  // wave-uniform row base (16 rows per wave)
      async16(Ab + (long long)(m0 + ra + srow) * lda + k0 + scol, &As[ra * 32]);
      async16(Bb + (long long)(n0 + ra + srow) * ldb + k0 + scol, &Bs[ra * 32]);
    }
    __syncthreads();
    bf16x8 av[4], bv[4];
#pragma unroll
    for (int mi = 0; mi < 4; mi++)
      av[mi] = *(const bf16x8*)&As[(wr * 64 + mi * 16 + m16) * 32 + q * 8];
#pragma unroll
    for (int ni = 0; ni < 4; ni++)
      bv[ni] = *(const bf16x8*)&Bs[(wc * 64 + ni * 16 + m16) * 32 + q * 8];
#pragma unroll
    for (int mi = 0; mi < 4; mi++)
#pragma unroll
      for (int ni = 0; ni < 4; ni++)
        acc[mi][ni] = __builtin_amdgcn_mfma_f32_16x16x32_bf16(
            av[mi], bv[ni], acc[mi][ni], 0, 0, 0);
    __syncthreads();
  }

#pragma unroll
  for (int mi = 0; mi < 4; mi++) {
#pragma unroll
    for (int r = 0; r < 4; r++) {
      int row = m0 + wr * 64 + mi * 16 + q * 4 + r;
      if (EPI == 0) {
        float* Cp = (float*)Cv + (long long)bat * sC +
                    (long long)sp * pstride + (long long)row * ldc;
#pragma unroll
        for (int ni = 0; ni < 4; ni++)
          Cp[n0 + wc * 64 + ni * 16 + m16] = acc[mi][ni][r];
      } else if (EPI == 2) {
        float* Cf = (float*)Cv + (long long)bat * sC + (long long)row * ldc;
#pragma unroll
        for (int ni = 0; ni < 4; ni++) {
          int col = n0 + wc * 64 + ni * 16 + m16;
          float v = acc[mi][ni][r] * scale;
          if (bias) v += bias[col];
          Cf[col] = v;
        }
      } else {
        u16* Cb = (u16*)Cv + (long long)bat * sC + (long long)row * ldc;
#pragma unroll
        for (int ni = 0; ni < 4; ni++) {
          int col = n0 + wc * 64 + ni * 16 + m16;
          float v = acc[mi][ni][r] + bias[col];
          if (EPI == 3) v = gelu_tanh(v);
          Cb[col] = f2bf(v);
        }
      }
    }
  }
}

// ---------------------------------------------------------------------------
// Split-K reduce + epilogue: out = [gelu](sum_s P[s] + bias) [+ res]
// ---------------------------------------------------------------------------
template <int S, int RES, int GELU, int OUTBF>
__global__ void reduce_k(const float* __restrict__ Pp, long long mn, int Nn,
                         const float* __restrict__ bias,
                         const float* __restrict__ res, void* __restrict__ out) {
  long long i = ((long long)blockIdx.x * 256 + threadIdx.x) * 4;
  if (i >= mn) return;
  float4 v = *(const float4*)(Pp + i);
#pragma unroll
  for (int s = 1; s < S; s++) {
    float4 u = *(const float4*)(Pp + (long long)s * mn + i);
    v.x += u.x; v.y += u.y; v.z += u.z; v.w += u.w;
  }
  int col = (int)(i % Nn);
  v.x += bias[col]; v.y += bias[col + 1]; v.z += bias[col + 2]; v.w += bias[col + 3];
  if (GELU) {
    v.x = gelu_tanh(v.x); v.y = gelu_tanh(v.y);
    v.z = gelu_tanh(v.z); v.w = gelu_tanh(v.w);
  }
  if (RES) {
    float4 r4 = *(const float4*)(res + i);
    v.x += r4.x; v.y += r4.y; v.z += r4.z; v.w += r4.w;
  }
  if (OUTBF) {
    ushort4 o; o.x = f2bf(v.x); o.y = f2bf(v.y); o.z = f2bf(v.z); o.w = f2bf(v.w);
    *(ushort4*)((u16*)out + i) = o;
  } else {
    *(float4*)((float*)out + i) = v;
  }
}

// ---------------------------------------------------------------------------
// Weight convert+transpose: in fp32 [K][N] -> out bf16 [N][K]. 32x32 tiles.
// ---------------------------------------------------------------------------
__global__ void wconv_k(const float* __restrict__ in, u16* __restrict__ out,
                        int K, int N) {
  __shared__ float tl[32][33];
  int n0 = blockIdx.x * 32, k0 = blockIdx.y * 32;
  int t = threadIdx.x;
  int r = t >> 5, c = t & 31;
#pragma unroll
  for (int i = 0; i < 4; i++)
    tl[r + 8 * i][c] = in[(long long)(k0 + r + 8 * i) * N + n0 + c];
  __syncthreads();
  int n = t >> 4, kp = (t & 15) * 2;
#pragma unroll
  for (int i = 0; i < 2; i++) {
    ushort2 o;
    o.x = f2bf(tl[kp][n + 16 * i]);
    o.y = f2bf(tl[kp + 1][n + 16 * i]);
    *(ushort2*)&out[(long long)(n0 + n + 16 * i) * K + k0 + kp] = o;
  }
}

// fp32 -> bf16 flat copy
__global__ void conv_k(const float* __restrict__ in, u16* __restrict__ out,
                       long long n) {
  long long i = ((long long)blockIdx.x * 256 + threadIdx.x) * 4;
  if (i >= n) return;
  float4 v = *(const float4*)(in + i);
  ushort4 o; o.x = f2bf(v.x); o.y = f2bf(v.y); o.z = f2bf(v.z); o.w = f2bf(v.w);
  *(ushort4*)&out[i] = o;
}

// V transpose per batch: in bf16 [b][512][128] -> out bf16 [b][128][512]
union U16x8 { uint4 v; u16 s[8]; };
__global__ void vtr_k(const u16* __restrict__ in, u16* __restrict__ out) {
  __shared__ u16 tl[64][65];
  int b = blockIdx.z;
  int m0 = blockIdx.x * 64;  // token dim (512)
  int d0 = blockIdx.y * 64;  // head dim (128)
  const u16* ib = in + (long long)b * SEG * 128;
  u16* ob = out + (long long)b * 128 * SEG;
  int t = threadIdx.x;
  int r = t >> 3, c8 = (t & 7) * 8;
#pragma unroll
  for (int i = 0; i < 2; i++) {
    U16x8 ld;
    ld.v = *(const uint4*)&ib[(long long)(m0 + r + 32 * i) * 128 + d0 + c8];
#pragma unroll
    for (int j = 0; j < 8; j++) tl[r + 32 * i][c8 + j] = ld.s[j];
  }
  __syncthreads();
  int d = t >> 3, m8 = (t & 7) * 8;
#pragma unroll
  for (int i = 0; i < 2; i++) {
    int dd = d + 32 * i;
    U16x8 st;
#pragma unroll
    for (int j = 0; j < 8; j++) st.s[j] = tl[m8 + j][dd];
    *(uint4*)&ob[(long long)(d0 + dd) * SEG + m0 + m8] = st.v;
  }
}

// ---------------------------------------------------------------------------
__global__ void coords_k(const int* __restrict__ g, int nimg,
                         int* __restrict__ rw, int* __restrict__ cl,
                         int* __restrict__ hh, int* __restrict__ ww, int N) {
  int t = blockIdx.x * 256 + threadIdx.x;
  if (t >= N) return;
  int c = 0, local = 0, H = 1, W = 1;
  for (int i = 0; i < nimg; i++) {
    int tpi = g[i * 3] * g[i * 3 + 1] * g[i * 3 + 2];
    if (t >= c && t < c + tpi) { local = t - c; H = g[i * 3 + 1]; W = g[i * 3 + 2]; }
    c += tpi;
  }
  int hw = H * W;
  int sp = local % hw;
  int mw = W >> 1;
  int gr = sp >> 2, intra = sp & 3;
  rw[t] = (gr / mw) * 2 + (intra >> 1);
  cl[t] = (gr % mw) * 2 + (intra & 1);
  hh[t] = H; ww[t] = W;
}

__global__ void peadd_k(float* __restrict__ x, const float* __restrict__ pe,
                        const int* __restrict__ rw, const int* __restrict__ cl,
                        const int* __restrict__ hh, const int* __restrict__ ww) {
  int n = blockIdx.x;
  int d = threadIdx.x * 4;
  int H = hh[n], W = ww[n];
  float rf = (H > 1) ? (float)rw[n] * (float)(GPOS - 1) / (float)(H - 1) : 0.f;
  float cf = (W > 1) ? (float)cl[n] * (float)(GPOS - 1) / (float)(W - 1) : 0.f;
  int r0 = (int)floorf(rf), c0 = (int)floorf(cf);
  int r1 = min(r0 + 1, GPOS - 1), c1 = min(c0 + 1, GPOS - 1);
  float wr = rf - (float)r0, wc = cf - (float)c0;
  float w00 = (1.f - wr) * (1.f - wc), w01 = (1.f - wr) * wc;
  float w10 = wr * (1.f - wc), w11 = wr * wc;
  float4 v00 = *(const float4*)(pe + (long long)(r0 * GPOS + c0) * DMODEL + d);
  float4 v01 = *(const float4*)(pe + (long long)(r0 * GPOS + c1) * DMODEL + d);
  float4 v10 = *(const float4*)(pe + (long long)(r1 * GPOS + c0) * DMODEL + d);
  float4 v11 = *(const float4*)(pe + (long long)(r1 * GPOS + c1) * DMODEL + d);
  float4 xv = *(float4*)(x + (long long)n * DMODEL + d);
  xv.x += w00 * v00.x + w01 * v01.x + w10 * v10.x + w11 * v11.x;
  xv.y += w00 * v00.y + w01 * v01.y + w10 * v10.y + w11 * v11.y;
  xv.z += w00 * v00.z + w01 * v01.z + w10 * v10.z + w11 * v11.z;
  xv.w += w00 * v00.w + w01 * v01.w + w10 * v10.w + w11 * v11.w;
  *(float4*)(x + (long long)n * DMODEL + d) = xv;
}

// LayerNorm fp32 in -> bf16 out (one 320-thread block per row of 1280)
__global__ void ln_k(const float* __restrict__ X, u16* __restrict__ Y,
                     const float* __restrict__ s, const float* __restrict__ b) {
  int row = blockIdx.x;
  int d = threadIdx.x * 4;
  const float* x = X + (long long)row * DMODEL;
  float4 v = *(const float4*)(x + d);
  float sum = v.x + v.y + v.z + v.w;
#pragma unroll
  for (int o = 32; o; o >>= 1) sum += __shfl_xor(sum, o);
  __shared__ float red[8];
  int wv = threadIdx.x >> 6, lnn = threadIdx.x & 63;
  if (lnn == 0) red[wv] = sum;
  __syncthreads();
  float mu = 0.f;
  for (int i = 0; i < 5; i++) mu += red[i];
  mu *= (1.f / DMODEL);
  float dx = v.x - mu, dy = v.y - mu, dz = v.z - mu, dw = v.w - mu;
  float s2 = dx * dx + dy * dy + dz * dz + dw * dw;
#pragma unroll
  for (int o = 32; o; o >>= 1) s2 += __shfl_xor(s2, o);
  __syncthreads();
  if (lnn == 0) red[wv] = s2;
  __syncthreads();
  float var = 0.f;
  for (int i = 0; i < 5; i++) var += red[i];
  var *= (1.f / DMODEL);
  float rs = rsqrtf(var + 1e-6f);
  ushort4 o4;
  o4.x = f2bf(dx * rs * s[d] + b[d]);
  o4.y = f2bf(dy * rs * s[d + 1] + b[d + 1]);
  o4.z = f2bf(dz * rs * s[d + 2] + b[d + 2]);
  o4.w = f2bf(dw * rs * s[d + 3] + b[d + 3]);
  *(ushort4*)(Y + (long long)row * DMODEL + d) = o4;
}

// RoPE from bf16 qkv -> qr/kr bf16 [h][N][96] (zero pad), v -> vp [h][N][128]
__global__ void rope_k(const u16* __restrict__ qkv, const int* __restrict__ rw,
                       const int* __restrict__ cl, u16* __restrict__ qr,
                       u16* __restrict__ kr, u16* __restrict__ vp, int N) {
  int n = blockIdx.x, h = blockIdx.y, t = threadIdx.x;
  const u16* src = qkv + (long long)n * (3 * DMODEL) + h * 80;
  long long ob96 = ((long long)h * N + n) * 96;
  long long ob128 = ((long long)h * N + n) * 128;
  if (t < 40) {
    float pos = (t < 20) ? (float)rw[n] : (float)cl[n];
    float infr = exp2f(-13.287712379549449f * (float)(t % 20) * 0.05f);
    float f = pos * infr;
    float cs = cosf(f), sn = sinf(f);
    float q0 = bf2f(src[t]), q1 = bf2f(src[t + 40]);
    qr[ob96 + t] = f2bf(q0 * cs - q1 * sn);
    qr[ob96 + t + 40] = f2bf(q1 * cs + q0 * sn);
    float k0 = bf2f(src[DMODEL + t]), k1 = bf2f(src[DMODEL + t + 40]);
    kr[ob96 + t] = f2bf(k0 * cs - k1 * sn);
    kr[ob96 + t + 40] = f2bf(k1 * cs + k0 * sn);
    vp[ob128 + t] = src[2 * DMODEL + t];
    vp[ob128 + t + 40] = src[2 * DMODEL + t + 40];
  } else {
    int u = t - 40;
    if (u < 16) { qr[ob96 + 80 + u] = 0; kr[ob96 + 80 + u] = 0; }
    vp[ob128 + 80 + u] = 0;
    vp[ob128 + 104 + u] = 0;
  }
}

// Row softmax over 512 (fp32 scores in, bf16 P out); one wave per row.
__global__ void softmax_k(const float* __restrict__ sc, u16* __restrict__ P) {
  long long base = ((long long)blockIdx.y * SEG + blockIdx.x) * SEG;
  int t = threadIdx.x;
  float4 a = *(const float4*)(sc + base + t * 4);
  float4 b = *(const float4*)(sc + base + 256 + t * 4);
  float mx = fmaxf(fmaxf(fmaxf(a.x, a.y), fmaxf(a.z, a.w)),
                   fmaxf(fmaxf(b.x, b.y), fmaxf(b.z, b.w)));
#pragma unroll
  for (int o = 32; o; o >>= 1) mx = fmaxf(mx, __shfl_xor(mx, o));
  a.x = __expf(a.x - mx); a.y = __expf(a.y - mx);
  a.z = __expf(a.z - mx); a.w = __expf(a.w - mx);
  b.x = __expf(b.x - mx); b.y = __expf(b.y - mx);
  b.z = __expf(b.z - mx); b.w = __expf(b.w - mx);
  float sm = a.x + a.y + a.z + a.w + b.x + b.y + b.z + b.w;
#pragma unroll
  for (int o = 32; o; o >>= 1) sm += __shfl_xor(sm, o);
  float r = 1.f / sm;
  ushort4 oa, ob;
  oa.x = f2bf(a.x * r); oa.y = f2bf(a.y * r); oa.z = f2bf(a.z * r); oa.w = f2bf(a.w * r);
  ob.x = f2bf(b.x * r); ob.y = f2bf(b.y * r); ob.z = f2bf(b.z * r); ob.w = f2bf(b.w * r);
  *(ushort4*)(P + base + t * 4) = oa;
  *(ushort4*)(P + base + 256 + t * 4) = ob;
}

// op fp32 [b=(h*4+seg)][m][128] -> o bf16 [n][1280]
__global__ void repack_k(const float* __restrict__ op, u16* __restrict__ o, int N) {
  int id = blockIdx.x * 256 + threadIdx.x;
  if (id >= N * DMODEL) return;
  int n = id / DMODEL, c = id % DMODEL;
  int h = c / 80, kk = c % 80;
  int seg = n >> 9, m = n & (SEG - 1);
  o[id] = f2bf(op[(((long long)h * 4 + seg) * SEG + m) * 128 + kk]);
}

// ---------------------------------------------------------------------------
static void gemm(hipStream_t st, int epi, const u16* A, const u16* B,
                 const float* bias, void* C, int M, int Nn, int Kd, int lda,
                 int ldb, int ldc, float scale, long long sA, long long sB,
                 long long sC, int batches, int nsplit) {
  dim3 g(Nn / 128, M / 128, batches * nsplit), blk(256);
  long long ps = (long long)M * Nn;
  switch (epi) {
    case 0: gemm_bt<0><<<g, blk, 0, st>>>(A, B, bias, C, Kd, lda, ldb, ldc, scale, sA, sB, sC, nsplit, ps); break;
    case 1: gemm_bt<1><<<g, blk, 0, st>>>(A, B, bias, C, Kd, lda, ldb, ldc, scale, sA, sB, sC, nsplit, ps); break;
    case 2: gemm_bt<2><<<g, blk, 0, st>>>(A, B, bias, C, Kd, lda, ldb, ldc, scale, sA, sB, sC, nsplit, ps); break;
    default: gemm_bt<3><<<g, blk, 0, st>>>(A, B, bias, C, Kd, lda, ldb, ldc, scale, sA, sB, sC, nsplit, ps); break;
  }
}

extern "C" void kernel_launch(void* const* d_in, const int* in_sizes, int n_in,
                              void* d_out, int out_size, void* d_ws, size_t ws_size,
                              hipStream_t stream) {
  const float* pixels = (const float*)d_in[0];
  const int* grid_thw = (const int*)d_in[1];
  const float* pos_embed = (const float*)d_in[2];
  const float* patch_w = (const float*)d_in[3];
  const float* patch_b = (const float*)d_in[4];
  const float* ln1_s = (const float*)d_in[5];
  const float* ln1_b = (const float*)d_in[6];
  const float* qkv_w = (const float*)d_in[7];
  const float* qkv_b = (const float*)d_in[8];
  const float* proj_w = (const float*)d_in[9];
  const float* proj_b = (const float*)d_in[10];
  const float* ln2_s = (const float*)d_in[11];
  const float* ln2_b = (const float*)d_in[12];
  const float* fc1_w = (const float*)d_in[13];
  const float* fc1_b = (const float*)d_in[14];
  const float* fc2_w = (const float*)d_in[15];
  const float* fc2_b = (const float*)d_in[16];
  const float* mns = (const float*)d_in[17];
  const float* mnb = (const float*)d_in[18];
  const float* mf1w = (const float*)d_in[19];
  const float* mf1b = (const float*)d_in[20];
  const float* mf2w = (const float*)d_in[21];
  const float* mf2b = (const float*)d_in[22];
  float* out = (float*)d_out;

  const int N = in_sizes[0] / 1536;  // 2048
  const int nimg = in_sizes[1] / 3;  // 4
  const int nseg = N / SEG;          // 4
  const int nb = NHEADS * nseg;      // 64

  char* w = (char*)d_ws;
  size_t off = 0;
  auto alloc = [&](size_t bytes) -> void* {
    void* p = w + off;
    off += (bytes + 255) & ~(size_t)255;
    return p;
  };
  int* rw = (int*)alloc((size_t)N * 4);
  int* cl = (int*)alloc((size_t)N * 4);
  int* hh = (int*)alloc((size_t)N * 4);
  int* ww = (int*)alloc((size_t)N * 4);
  float* x = (float*)alloc((size_t)N * DMODEL * 4);
  u16* h = (u16*)alloc((size_t)N * DMODEL * 2);
  u16* pixbf = (u16*)alloc((size_t)N * 1536 * 2);      // mfc2T overlay base
  u16* patchT = (u16*)alloc((size_t)DMODEL * 1536 * 2);
  u16* qkvT = (u16*)alloc((size_t)3 * DMODEL * DMODEL * 2);
  u16* projT = (u16*)alloc((size_t)DMODEL * DMODEL * 2);
  u16* fc1T = (u16*)alloc((size_t)FDIM * DMODEL * 2);
  u16* fc2T = (u16*)alloc((size_t)DMODEL * FDIM * 2);
  u16* qkvb = (u16*)alloc((size_t)N * 3 * DMODEL * 2);  // mfc1T overlay base
  u16* qr = (u16*)alloc((size_t)NHEADS * N * 96 * 2);
  u16* kr = (u16*)alloc((size_t)NHEADS * N * 96 * 2);
  u16* vp = (u16*)alloc((size_t)NHEADS * N * 128 * 2);
  u16* vpT = (u16*)alloc((size_t)NHEADS * N * 128 * 2);
  float* op = (float*)alloc((size_t)nb * SEG * 128 * 4);
  u16* o = (u16*)alloc((size_t)N * DMODEL * 2);
  float* bigA = (float*)alloc((size_t)nb * SEG * SEG * 4);  // scores / ffb / mf
  float* bigB = (float*)alloc((size_t)nb * SEG * SEG * 2);  // P / split partials
  (void)ws_size;
  // overlays (lifetimes disjoint with originals)
  u16* mfc1T = qkvb;         // 52.4 MB over qkvb..op (61.9 MB)
  u16* mfc2T = pixbf;        // 21.0 MB over pixbf..projT (23.3 MB)
  u16* ffb = (u16*)bigA;     // fc1 out 21 MB inside 67 MB
  u16* mf = (u16*)bigA;      // merger hidden 5.2 MB
  u16* P = (u16*)bigB;       // softmax out bf16
  float* part = bigB;        // split-K partials (<= 21 MB)

  const float iscale = 0.11180339887498949f;  // 80^-0.5

  coords_k<<<dim3((N + 255) / 256), 256, 0, stream>>>(grid_thw, nimg, rw, cl, hh, ww, N);
  conv_k<<<dim3((int)(((long long)N * 1536 / 4 + 255) / 256)), 256, 0, stream>>>(
      pixels, pixbf, (long long)N * 1536);
  wconv_k<<<dim3(DMODEL / 32, 1536 / 32), 256, 0, stream>>>(patch_w, patchT, 1536, DMODEL);
  // patch embed, split-K=2
  gemm(stream, 0, pixbf, patchT, nullptr, part, N, DMODEL, 1536, 1536, 1536,
       DMODEL, 1.f, 0, 0, 0, 1, 2);
  reduce_k<2, 0, 0, 0><<<dim3((int)(((long long)N * DMODEL / 4 + 255) / 256)), 256, 0, stream>>>(
      part, (long long)N * DMODEL, DMODEL, patch_b, nullptr, x);
  peadd_k<<<dim3(N), 320, 0, stream>>>(x, pos_embed, rw, cl, hh, ww);

  for (int l = 0; l < 4; l++) {
    wconv_k<<<dim3(3 * DMODEL / 32, DMODEL / 32), 256, 0, stream>>>(
        qkv_w + (size_t)l * DMODEL * 3 * DMODEL, qkvT, DMODEL, 3 * DMODEL);
    wconv_k<<<dim3(DMODEL / 32, DMODEL / 32), 256, 0, stream>>>(
        proj_w + (size_t)l * DMODEL * DMODEL, projT, DMODEL, DMODEL);
    wconv_k<<<dim3(FDIM / 32, DMODEL / 32), 256, 0, stream>>>(
        fc1_w + (size_t)l * DMODEL * FDIM, fc1T, DMODEL, FDIM);
    wconv_k<<<dim3(DMODEL / 32, FDIM / 32), 256, 0, stream>>>(
        fc2_w + (size_t)l * FDIM * DMODEL, fc2T, FDIM, DMODEL);

    ln_k<<<dim3(N), 320, 0, stream>>>(x, h, ln1_s + l * DMODEL, ln1_b + l * DMODEL);
    gemm(stream, 1, h, qkvT, qkv_b + (size_t)l * 3 * DMODEL, qkvb, N, 3 * DMODEL,
         DMODEL, DMODEL, DMODEL, 3 * DMODEL, 1.f, 0, 0, 0, 1, 1);
    rope_k<<<dim3(N, NHEADS), 64, 0, stream>>>(qkvb, rw, cl, qr, kr, vp, N);
    // scores = iscale * Q.K^T per (head,seg)
    gemm(stream, 2, qr, kr, nullptr, bigA, SEG, SEG, 96, 96, 96, SEG, iscale,
         (long long)SEG * 96, (long long)SEG * 96, (long long)SEG * SEG, nb, 1);
    softmax_k<<<dim3(SEG, nb), 64, 0, stream>>>(bigA, P);
    vtr_k<<<dim3(8, 2, nb), 256, 0, stream>>>(vp, vpT);
    // O = P.V
    gemm(stream, 2, P, vpT, nullptr, op, SEG, 128, SEG, SEG, SEG, 128, 1.f,
         (long long)SEG * SEG, (long long)128 * SEG, (long long)SEG * 128, nb, 1);
    repack_k<<<dim3((N * DMODEL + 255) / 256), 256, 0, stream>>>(op, o, N);
    // proj, split-K=2, then + bias + residual
    gemm(stream, 0, o, projT, nullptr, part, N, DMODEL, DMODEL, DMODEL, DMODEL,
         DMODEL, 1.f, 0, 0, 0, 1, 2);
    reduce_k<2, 1, 0, 0><<<dim3((int)(((long long)N * DMODEL / 4 + 255) / 256)), 256, 0, stream>>>(
        part, (long long)N * DMODEL, DMODEL, proj_b + (size_t)l * DMODEL, x, x);
    ln_k<<<dim3(N), 320, 0, stream>>>(x, h, ln2_s + l * DMODEL, ln2_b + l * DMODEL);
    // fc1 fused bias+gelu -> bf16
    gemm(stream, 3, h, fc1T, fc1_b + (size_t)l * FDIM, ffb, N, FDIM, DMODEL,
         DMODEL, DMODEL, FDIM, 1.f, 0, 0, 0, 1, 1);
    // fc2 split-K=2 + bias + residual
    gemm(stream, 0, ffb, fc2T, nullptr, part, N, DMODEL, FDIM, FDIM, FDIM,
         DMODEL, 1.f, 0, 0, 0, 1, 2);
    reduce_k<2, 1, 0, 0><<<dim3((int)(((long long)N * DMODEL / 4 + 255) / 256)), 256, 0, stream>>>(
        part, (long long)N * DMODEL, DMODEL, fc2_b + (size_t)l * DMODEL, x, x);
  }

  // merger
  ln_k<<<dim3(N), 320, 0, stream>>>(x, h, mns, mnb);  // h viewed as [512][5120]
  const int Mm = N / 4;  // 512
  wconv_k<<<dim3(FDIM / 32, FDIM / 32), 256, 0, stream>>>(mf1w, mfc1T, FDIM, FDIM);
  gemm(stream, 0, h, mfc1T, nullptr, part, Mm, FDIM, FDIM, FDIM, FDIM, FDIM,
       1.f, 0, 0, 0, 1, 2);
  reduce_k<2, 0, 1, 1><<<dim3((int)(((long long)Mm * FDIM / 4 + 255) / 256)), 256, 0, stream>>>(
      part, (long long)Mm * FDIM, FDIM, mf1b, nullptr, mf);
  wconv_k<<<dim3(2048 / 32, FDIM / 32), 256, 0, stream>>>(mf2w, mfc2T, FDIM, 2048);
  gemm(stream, 0, mf, mfc2T, nullptr, part, Mm, 2048, FDIM, FDIM, FDIM, 2048,
       1.f, 0, 0, 0, 1, 4);
  reduce_k<4, 0, 0, 0><<<dim3((int)(((long long)Mm * 2048 / 4 + 255) / 256)), 256, 0, stream>>>(
      part, (long long)Mm * 2048, 2048, mf2b, nullptr, out);
}

// Round 3
// 1651.584 us; speedup vs baseline: 1.9002x; 1.1058x over previous
//
#include <hip/hip_runtime.h>
#include <math.h>

#define DMODEL 1280
#define NHEADS 16
#define FDIM   5120
#define GPOS   48
#define SEG    512

typedef __attribute__((ext_vector_type(8))) short bf16x8;
typedef __attribute__((ext_vector_type(4))) float f32x4;
typedef unsigned short u16;

__device__ __forceinline__ u16 f2bf(float f) {
  unsigned int u = __float_as_uint(f);
  u = (u + 0x7FFFu + ((u >> 16) & 1u)) >> 16;  // RNE
  return (u16)u;
}
__device__ __forceinline__ float bf2f(u16 u) {
  return __uint_as_float((unsigned int)u << 16);
}
__device__ __forceinline__ float gelu_tanh(float x) {
  // tanh via exp, saturating form (no inf/inf NaN)
  float u = 0.7978845608028654f * (x + 0.044715f * x * x * x);
  float t = __expf(2.f * u);
  float th = 1.f - 2.f / (t + 1.f);
  return 0.5f * x * (1.f + th);
}

typedef const __attribute__((address_space(1))) unsigned int* gas_t;
typedef __attribute__((address_space(3))) unsigned int* las_t;
__device__ __forceinline__ void async16(const void* g, void* l) {
  __builtin_amdgcn_global_load_lds((gas_t)g, (las_t)l, 16, 0, 0);
}

// ---------------------------------------------------------------------------
// bf16 GEMM, 128x128 tile, 4 waves, 4x4 MFMA 16x16x32, double-buffered LDS
// (single barrier per k-step; stage(k+1) issued right after the barrier so
// global_load_lds flight overlaps ds_read+MFMA of step k).
// A: [M][K] bf16 (lda). B: [N][K] bf16 (ldb). Grid: x=M-tile (fastest, so
// consecutive blocks share a B n-tile for L2 reuse), y=N-tile, z=batch*split.
// EPI: 0 = bf16 raw partial (split-K planes, stride pstride);
//      1 = bf16 +bias; 2 = fp32 *scale (+bias if non-null); 3 = bf16 +bias+gelu
// ---------------------------------------------------------------------------
template <int EPI>
__global__ __launch_bounds__(256) void gemm_bt(
    const u16* __restrict__ A, const u16* __restrict__ B,
    const float* __restrict__ bias, void* __restrict__ Cv,
    int Kd, int lda, int ldb, int ldc, float scale,
    long long sA, long long sB, long long sC, int nsplit, long long pstride) {
  __shared__ __align__(16) u16 As[2][128 * 32];
  __shared__ __align__(16) u16 Bs[2][128 * 32];
  const int bz = blockIdx.z;
  const int bat = bz / nsplit, sp = bz - bat * nsplit;
  const int Ks = Kd / nsplit;
  const u16* Ab = A + (long long)bat * sA + (long long)sp * Ks;
  const u16* Bb = B + (long long)bat * sB + (long long)sp * Ks;
  const int m0 = blockIdx.x * 128, n0 = blockIdx.y * 128;
  const int t = threadIdx.x, ln = t & 63, w = t >> 6;
  const int srow = ln >> 2, scol = (ln & 3) * 8;
  const int m16 = ln & 15, q = ln >> 4;
  const int wr = w >> 1, wc = w & 1;

  f32x4 acc[4][4];
#pragma unroll
  for (int i = 0; i < 4; i++)
#pragma unroll
    for (int j = 0; j < 4; j++)
#pragma unroll
      for (int r = 0; r < 4; r++) acc[i][j][r] = 0.f;

  auto stage = [&](int k0, int p) {
#pragma unroll
    for (int it = 0; it < 2; it++) {
      int ra = it * 64 + w * 16;  // wave-uniform row base (16 rows per wave)
      async16(Ab + (long long)(m0 + ra + srow) * lda + k0 + scol, &As[p][ra * 32]);
      async16(Bb + (long long)(n0 + ra + srow) * ldb + k0 + scol, &Bs[p][ra * 32]);
    }
  };

  stage(0, 0);
  int p = 0;
  for (int k0 = 0; k0 < Ks; k0 += 32) {
    __syncthreads();                 // buf[p] complete; prior ds_reads drained
    if (k0 + 32 < Ks) stage(k0 + 32, p ^ 1);  // overlap with MFMA below
    bf16x8 av[4], bv[4];
#pragma unroll
    for (int mi = 0; mi < 4; mi++)
      av[mi] = *(const bf16x8*)&As[p][(wr * 64 + mi * 16 + m16) * 32 + q * 8];
#pragma unroll
    for (int ni = 0; ni < 4; ni++)
      bv[ni] = *(const bf16x8*)&Bs[p][(wc * 64 + ni * 16 + m16) * 32 + q * 8];
#pragma unroll
    for (int mi = 0; mi < 4; mi++)
#pragma unroll
      for (int ni = 0; ni < 4; ni++)
        acc[mi][ni] = __builtin_amdgcn_mfma_f32_16x16x32_bf16(
            av[mi], bv[ni], acc[mi][ni], 0, 0, 0);
    p ^= 1;
  }

#pragma unroll
  for (int mi = 0; mi < 4; mi++) {
#pragma unroll
    for (int r = 0; r < 4; r++) {
      int row = m0 + wr * 64 + mi * 16 + q * 4 + r;
      if (EPI == 0) {
        u16* Cp = (u16*)Cv + (long long)bat * sC +
                  (long long)sp * pstride + (long long)row * ldc;
#pragma unroll
        for (int ni = 0; ni < 4; ni++)
          Cp[n0 + wc * 64 + ni * 16 + m16] = f2bf(acc[mi][ni][r]);
      } else if (EPI == 2) {
        float* Cf = (float*)Cv + (long long)bat * sC + (long long)row * ldc;
#pragma unroll
        for (int ni = 0; ni < 4; ni++) {
          int col = n0 + wc * 64 + ni * 16 + m16;
          float v = acc[mi][ni][r] * scale;
          if (bias) v += bias[col];
          Cf[col] = v;
        }
      } else {
        u16* Cb = (u16*)Cv + (long long)bat * sC + (long long)row * ldc;
#pragma unroll
        for (int ni = 0; ni < 4; ni++) {
          int col = n0 + wc * 64 + ni * 16 + m16;
          float v = acc[mi][ni][r] + bias[col];
          if (EPI == 3) v = gelu_tanh(v);
          Cb[col] = f2bf(v);
        }
      }
    }
  }
}

// ---------------------------------------------------------------------------
// Split-K reduce + epilogue (bf16 partials): out = [gelu](sum + bias) [+ res]
// ---------------------------------------------------------------------------
template <int S, int RES, int GELU, int OUTBF>
__global__ void reduce_k(const u16* __restrict__ Pp, long long mn, int Nn,
                         const float* __restrict__ bias,
                         const float* __restrict__ res, void* __restrict__ out) {
  long long i = ((long long)blockIdx.x * 256 + threadIdx.x) * 4;
  if (i >= mn) return;
  float vx = 0.f, vy = 0.f, vz = 0.f, vw = 0.f;
#pragma unroll
  for (int s = 0; s < S; s++) {
    ushort4 u4 = *(const ushort4*)(Pp + (long long)s * mn + i);
    vx += bf2f(u4.x); vy += bf2f(u4.y); vz += bf2f(u4.z); vw += bf2f(u4.w);
  }
  int col = (int)(i % Nn);
  vx += bias[col]; vy += bias[col + 1]; vz += bias[col + 2]; vw += bias[col + 3];
  if (GELU) {
    vx = gelu_tanh(vx); vy = gelu_tanh(vy);
    vz = gelu_tanh(vz); vw = gelu_tanh(vw);
  }
  if (RES) {
    float4 r4 = *(const float4*)(res + i);
    vx += r4.x; vy += r4.y; vz += r4.z; vw += r4.w;
  }
  if (OUTBF) {
    ushort4 o; o.x = f2bf(vx); o.y = f2bf(vy); o.z = f2bf(vz); o.w = f2bf(vw);
    *(ushort4*)((u16*)out + i) = o;
  } else {
    float4 o; o.x = vx; o.y = vy; o.z = vz; o.w = vw;
    *(float4*)((float*)out + i) = o;
  }
}

// ---------------------------------------------------------------------------
// Weight convert+transpose: in fp32 [K][N] -> out bf16 [N][K]. 32x32 tiles.
// ---------------------------------------------------------------------------
__global__ void wconv_k(const float* __restrict__ in, u16* __restrict__ out,
                        int K, int N) {
  __shared__ float tl[32][33];
  int n0 = blockIdx.x * 32, k0 = blockIdx.y * 32;
  int t = threadIdx.x;
  int r = t >> 5, c = t & 31;
#pragma unroll
  for (int i = 0; i < 4; i++)
    tl[r + 8 * i][c] = in[(long long)(k0 + r + 8 * i) * N + n0 + c];
  __syncthreads();
  int n = t >> 4, kp = (t & 15) * 2;
#pragma unroll
  for (int i = 0; i < 2; i++) {
    ushort2 o;
    o.x = f2bf(tl[kp][n + 16 * i]);
    o.y = f2bf(tl[kp + 1][n + 16 * i]);
    *(ushort2*)&out[(long long)(n0 + n + 16 * i) * K + k0 + kp] = o;
  }
}

// fp32 -> bf16 flat copy
__global__ void conv_k(const float* __restrict__ in, u16* __restrict__ out,
                       long long n) {
  long long i = ((long long)blockIdx.x * 256 + threadIdx.x) * 4;
  if (i >= n) return;
  float4 v = *(const float4*)(in + i);
  ushort4 o; o.x = f2bf(v.x); o.y = f2bf(v.y); o.z = f2bf(v.z); o.w = f2bf(v.w);
  *(ushort4*)&out[i] = o;
}

// V transpose per batch: in bf16 [b][512][128] -> out bf16 [b][128][512]
union U16x8 { uint4 v; u16 s[8]; };
__global__ void vtr_k(const u16* __restrict__ in, u16* __restrict__ out) {
  __shared__ u16 tl[64][65];
  int b = blockIdx.z;
  int m0 = blockIdx.x * 64;
  int d0 = blockIdx.y * 64;
  const u16* ib = in + (long long)b * SEG * 128;
  u16* ob = out + (long long)b * 128 * SEG;
  int t = threadIdx.x;
  int r = t >> 3, c8 = (t & 7) * 8;
#pragma unroll
  for (int i = 0; i < 2; i++) {
    U16x8 ld;
    ld.v = *(const uint4*)&ib[(long long)(m0 + r + 32 * i) * 128 + d0 + c8];
#pragma unroll
    for (int j = 0; j < 8; j++) tl[r + 32 * i][c8 + j] = ld.s[j];
  }
  __syncthreads();
  int d = t >> 3, m8 = (t & 7) * 8;
#pragma unroll
  for (int i = 0; i < 2; i++) {
    int dd = d + 32 * i;
    U16x8 st;
#pragma unroll
    for (int j = 0; j < 8; j++) st.s[j] = tl[m8 + j][dd];
    *(uint4*)&ob[(long long)(d0 + dd) * SEG + m0 + m8] = st.v;
  }
}

// ---------------------------------------------------------------------------
__global__ void coords_k(const int* __restrict__ g, int nimg,
                         int* __restrict__ rw, int* __restrict__ cl,
                         int* __restrict__ hh, int* __restrict__ ww, int N) {
  int t = blockIdx.x * 256 + threadIdx.x;
  if (t >= N) return;
  int c = 0, local = 0, H = 1, W = 1;
  for (int i = 0; i < nimg; i++) {
    int tpi = g[i * 3] * g[i * 3 + 1] * g[i * 3 + 2];
    if (t >= c && t < c + tpi) { local = t - c; H = g[i * 3 + 1]; W = g[i * 3 + 2]; }
    c += tpi;
  }
  int hw = H * W;
  int sp = local % hw;
  int mw = W >> 1;
  int gr = sp >> 2, intra = sp & 3;
  rw[t] = (gr / mw) * 2 + (intra >> 1);
  cl[t] = (gr % mw) * 2 + (intra & 1);
  hh[t] = H; ww[t] = W;
}

__global__ void peadd_k(float* __restrict__ x, const float* __restrict__ pe,
                        const int* __restrict__ rw, const int* __restrict__ cl,
                        const int* __restrict__ hh, const int* __restrict__ ww) {
  int n = blockIdx.x;
  int d = threadIdx.x * 4;
  int H = hh[n], W = ww[n];
  float rf = (H > 1) ? (float)rw[n] * (float)(GPOS - 1) / (float)(H - 1) : 0.f;
  float cf = (W > 1) ? (float)cl[n] * (float)(GPOS - 1) / (float)(W - 1) : 0.f;
  int r0 = (int)floorf(rf), c0 = (int)floorf(cf);
  int r1 = min(r0 + 1, GPOS - 1), c1 = min(c0 + 1, GPOS - 1);
  float wr = rf - (float)r0, wc = cf - (float)c0;
  float w00 = (1.f - wr) * (1.f - wc), w01 = (1.f - wr) * wc;
  float w10 = wr * (1.f - wc), w11 = wr * wc;
  float4 v00 = *(const float4*)(pe + (long long)(r0 * GPOS + c0) * DMODEL + d);
  float4 v01 = *(const float4*)(pe + (long long)(r0 * GPOS + c1) * DMODEL + d);
  float4 v10 = *(const float4*)(pe + (long long)(r1 * GPOS + c0) * DMODEL + d);
  float4 v11 = *(const float4*)(pe + (long long)(r1 * GPOS + c1) * DMODEL + d);
  float4 xv = *(float4*)(x + (long long)n * DMODEL + d);
  xv.x += w00 * v00.x + w01 * v01.x + w10 * v10.x + w11 * v11.x;
  xv.y += w00 * v00.y + w01 * v01.y + w10 * v10.y + w11 * v11.y;
  xv.z += w00 * v00.z + w01 * v01.z + w10 * v10.z + w11 * v11.z;
  xv.w += w00 * v00.w + w01 * v01.w + w10 * v10.w + w11 * v11.w;
  *(float4*)(x + (long long)n * DMODEL + d) = xv;
}

// LayerNorm fp32 in -> bf16 out (one 320-thread block per row of 1280)
__global__ void ln_k(const float* __restrict__ X, u16* __restrict__ Y,
                     const float* __restrict__ s, const float* __restrict__ b) {
  int row = blockIdx.x;
  int d = threadIdx.x * 4;
  const float* x = X + (long long)row * DMODEL;
  float4 v = *(const float4*)(x + d);
  float sum = v.x + v.y + v.z + v.w;
#pragma unroll
  for (int o = 32; o; o >>= 1) sum += __shfl_xor(sum, o);
  __shared__ float red[8];
  int wv = threadIdx.x >> 6, lnn = threadIdx.x & 63;
  if (lnn == 0) red[wv] = sum;
  __syncthreads();
  float mu = 0.f;
  for (int i = 0; i < 5; i++) mu += red[i];
  mu *= (1.f / DMODEL);
  float dx = v.x - mu, dy = v.y - mu, dz = v.z - mu, dw = v.w - mu;
  float s2 = dx * dx + dy * dy + dz * dz + dw * dw;
#pragma unroll
  for (int o = 32; o; o >>= 1) s2 += __shfl_xor(s2, o);
  __syncthreads();
  if (lnn == 0) red[wv] = s2;
  __syncthreads();
  float var = 0.f;
  for (int i = 0; i < 5; i++) var += red[i];
  var *= (1.f / DMODEL);
  float rs = rsqrtf(var + 1e-6f);
  ushort4 o4;
  o4.x = f2bf(dx * rs * s[d] + b[d]);
  o4.y = f2bf(dy * rs * s[d + 1] + b[d + 1]);
  o4.z = f2bf(dz * rs * s[d + 2] + b[d + 2]);
  o4.w = f2bf(dw * rs * s[d + 3] + b[d + 3]);
  *(ushort4*)(Y + (long long)row * DMODEL + d) = o4;
}

// RoPE from bf16 qkv -> qr/kr bf16 [h][N][96] (zero pad), v -> vp [h][N][128]
__global__ void rope_k(const u16* __restrict__ qkv, const int* __restrict__ rw,
                       const int* __restrict__ cl, u16* __restrict__ qr,
                       u16* __restrict__ kr, u16* __restrict__ vp, int N) {
  int n = blockIdx.x, h = blockIdx.y, t = threadIdx.x;
  const u16* src = qkv + (long long)n * (3 * DMODEL) + h * 80;
  long long ob96 = ((long long)h * N + n) * 96;
  long long ob128 = ((long long)h * N + n) * 128;
  if (t < 40) {
    float pos = (t < 20) ? (float)rw[n] : (float)cl[n];
    float infr = exp2f(-13.287712379549449f * (float)(t % 20) * 0.05f);
    float f = pos * infr;
    float cs = cosf(f), sn = sinf(f);
    float q0 = bf2f(src[t]), q1 = bf2f(src[t + 40]);
    qr[ob96 + t] = f2bf(q0 * cs - q1 * sn);
    qr[ob96 + t + 40] = f2bf(q1 * cs + q0 * sn);
    float k0 = bf2f(src[DMODEL + t]), k1 = bf2f(src[DMODEL + t + 40]);
    kr[ob96 + t] = f2bf(k0 * cs - k1 * sn);
    kr[ob96 + t + 40] = f2bf(k1 * cs + k0 * sn);
    vp[ob128 + t] = src[2 * DMODEL + t];
    vp[ob128 + t + 40] = src[2 * DMODEL + t + 40];
  } else {
    int u = t - 40;
    if (u < 16) { qr[ob96 + 80 + u] = 0; kr[ob96 + 80 + u] = 0; }
    vp[ob128 + 80 + u] = 0;
    vp[ob128 + 104 + u] = 0;
  }
}

// Row softmax over 512 (fp32 scores in, bf16 P out); one wave per row.
__global__ void softmax_k(const float* __restrict__ sc, u16* __restrict__ P) {
  long long base = ((long long)blockIdx.y * SEG + blockIdx.x) * SEG;
  int t = threadIdx.x;
  float4 a = *(const float4*)(sc + base + t * 4);
  float4 b = *(const float4*)(sc + base + 256 + t * 4);
  float mx = fmaxf(fmaxf(fmaxf(a.x, a.y), fmaxf(a.z, a.w)),
                   fmaxf(fmaxf(b.x, b.y), fmaxf(b.z, b.w)));
#pragma unroll
  for (int o = 32; o; o >>= 1) mx = fmaxf(mx, __shfl_xor(mx, o));
  a.x = __expf(a.x - mx); a.y = __expf(a.y - mx);
  a.z = __expf(a.z - mx); a.w = __expf(a.w - mx);
  b.x = __expf(b.x - mx); b.y = __expf(b.y - mx);
  b.z = __expf(b.z - mx); b.w = __expf(b.w - mx);
  float sm = a.x + a.y + a.z + a.w + b.x + b.y + b.z + b.w;
#pragma unroll
  for (int o = 32; o; o >>= 1) sm += __shfl_xor(sm, o);
  float r = 1.f / sm;
  ushort4 oa, ob;
  oa.x = f2bf(a.x * r); oa.y = f2bf(a.y * r); oa.z = f2bf(a.z * r); oa.w = f2bf(a.w * r);
  ob.x = f2bf(b.x * r); ob.y = f2bf(b.y * r); ob.z = f2bf(b.z * r); ob.w = f2bf(b.w * r);
  *(ushort4*)(P + base + t * 4) = oa;
  *(ushort4*)(P + base + 256 + t * 4) = ob;
}

// op bf16 partials [b=(h*4+seg)][2][m][128] -> o bf16 [n][1280]
__global__ void repack_k(const u16* __restrict__ op, u16* __restrict__ o, int N) {
  int id = blockIdx.x * 256 + threadIdx.x;
  if (id >= N * DMODEL) return;
  int n = id / DMODEL, c = id % DMODEL;
  int h = c / 80, kk = c % 80;
  int seg = n >> 9, m = n & (SEG - 1);
  long long base = (long long)(h * 4 + seg) * (2 * SEG * 128) + (long long)m * 128 + kk;
  o[id] = f2bf(bf2f(op[base]) + bf2f(op[base + SEG * 128]));
}

// ---------------------------------------------------------------------------
static void gemm(hipStream_t st, int epi, const u16* A, const u16* B,
                 const float* bias, void* C, int M, int Nn, int Kd, int lda,
                 int ldb, int ldc, float scale, long long sA, long long sB,
                 long long sC, int batches, int nsplit) {
  dim3 g(M / 128, Nn / 128, batches * nsplit), blk(256);
  long long ps = (long long)M * Nn;
  switch (epi) {
    case 0: gemm_bt<0><<<g, blk, 0, st>>>(A, B, bias, C, Kd, lda, ldb, ldc, scale, sA, sB, sC, nsplit, ps); break;
    case 1: gemm_bt<1><<<g, blk, 0, st>>>(A, B, bias, C, Kd, lda, ldb, ldc, scale, sA, sB, sC, nsplit, ps); break;
    case 2: gemm_bt<2><<<g, blk, 0, st>>>(A, B, bias, C, Kd, lda, ldb, ldc, scale, sA, sB, sC, nsplit, ps); break;
    default: gemm_bt<3><<<g, blk, 0, st>>>(A, B, bias, C, Kd, lda, ldb, ldc, scale, sA, sB, sC, nsplit, ps); break;
  }
}

extern "C" void kernel_launch(void* const* d_in, const int* in_sizes, int n_in,
                              void* d_out, int out_size, void* d_ws, size_t ws_size,
                              hipStream_t stream) {
  const float* pixels = (const float*)d_in[0];
  const int* grid_thw = (const int*)d_in[1];
  const float* pos_embed = (const float*)d_in[2];
  const float* patch_w = (const float*)d_in[3];
  const float* patch_b = (const float*)d_in[4];
  const float* ln1_s = (const float*)d_in[5];
  const float* ln1_b = (const float*)d_in[6];
  const float* qkv_w = (const float*)d_in[7];
  const float* qkv_b = (const float*)d_in[8];
  const float* proj_w = (const float*)d_in[9];
  const float* proj_b = (const float*)d_in[10];
  const float* ln2_s = (const float*)d_in[11];
  const float* ln2_b = (const float*)d_in[12];
  const float* fc1_w = (const float*)d_in[13];
  const float* fc1_b = (const float*)d_in[14];
  const float* fc2_w = (const float*)d_in[15];
  const float* fc2_b = (const float*)d_in[16];
  const float* mns = (const float*)d_in[17];
  const float* mnb = (const float*)d_in[18];
  const float* mf1w = (const float*)d_in[19];
  const float* mf1b = (const float*)d_in[20];
  const float* mf2w = (const float*)d_in[21];
  const float* mf2b = (const float*)d_in[22];
  float* out = (float*)d_out;

  const int N = in_sizes[0] / 1536;  // 2048
  const int nimg = in_sizes[1] / 3;  // 4
  const int nseg = N / SEG;          // 4
  const int nb = NHEADS * nseg;      // 64

  char* w = (char*)d_ws;
  size_t off = 0;
  auto alloc = [&](size_t bytes) -> void* {
    void* p = w + off;
    off += (bytes + 255) & ~(size_t)255;
    return p;
  };
  int* rw = (int*)alloc((size_t)N * 4);
  int* cl = (int*)alloc((size_t)N * 4);
  int* hh = (int*)alloc((size_t)N * 4);
  int* ww = (int*)alloc((size_t)N * 4);
  float* x = (float*)alloc((size_t)N * DMODEL * 4);
  u16* h = (u16*)alloc((size_t)N * DMODEL * 2);
  u16* pixbf = (u16*)alloc((size_t)N * 1536 * 2);      // mfc2T overlay base
  u16* patchT = (u16*)alloc((size_t)DMODEL * 1536 * 2);
  u16* qkvT = (u16*)alloc((size_t)3 * DMODEL * DMODEL * 2);
  u16* projT = (u16*)alloc((size_t)DMODEL * DMODEL * 2);
  u16* fc1T = (u16*)alloc((size_t)FDIM * DMODEL * 2);
  u16* fc2T = (u16*)alloc((size_t)DMODEL * FDIM * 2);
  u16* qkvb = (u16*)alloc((size_t)N * 3 * DMODEL * 2);  // mfc1T overlay base
  u16* qr = (u16*)alloc((size_t)NHEADS * N * 96 * 2);
  u16* kr = (u16*)alloc((size_t)NHEADS * N * 96 * 2);
  u16* vp = (u16*)alloc((size_t)NHEADS * N * 128 * 2);
  u16* vpT = (u16*)alloc((size_t)NHEADS * N * 128 * 2);
  u16* op = (u16*)alloc((size_t)nb * 2 * SEG * 128 * 2);  // PV split-2 partials
  u16* o = (u16*)alloc((size_t)N * DMODEL * 2);
  float* bigA = (float*)alloc((size_t)nb * SEG * SEG * 4);  // scores / ffb / mf
  float* bigB = (float*)alloc((size_t)nb * SEG * SEG * 2);  // P / split partials
  (void)ws_size;
  // overlays (lifetimes disjoint with originals)
  u16* mfc1T = qkvb;         // 52.4 MB over qkvb..op region
  u16* mfc2T = pixbf;        // 21.0 MB over pixbf..projT
  u16* ffb = (u16*)bigA;     // fc1 out 21 MB inside 67 MB
  u16* mf = (u16*)bigA;      // merger hidden 5.2 MB
  u16* P = (u16*)bigB;       // softmax out bf16 (33.5 MB)
  u16* part = (u16*)bigB;    // split-K bf16 partials (<= 21 MB)

  const float iscale = 0.11180339887498949f;  // 80^-0.5

  coords_k<<<dim3((N + 255) / 256), 256, 0, stream>>>(grid_thw, nimg, rw, cl, hh, ww, N);
  conv_k<<<dim3((int)(((long long)N * 1536 / 4 + 255) / 256)), 256, 0, stream>>>(
      pixels, pixbf, (long long)N * 1536);
  wconv_k<<<dim3(DMODEL / 32, 1536 / 32), 256, 0, stream>>>(patch_w, patchT, 1536, DMODEL);
  // patch embed, split-K=4 (640 blocks)
  gemm(stream, 0, pixbf, patchT, nullptr, part, N, DMODEL, 1536, 1536, 1536,
       DMODEL, 1.f, 0, 0, 0, 1, 4);
  reduce_k<4, 0, 0, 0><<<dim3((int)(((long long)N * DMODEL / 4 + 255) / 256)), 256, 0, stream>>>(
      part, (long long)N * DMODEL, DMODEL, patch_b, nullptr, x);
  peadd_k<<<dim3(N), 320, 0, stream>>>(x, pos_embed, rw, cl, hh, ww);

  for (int l = 0; l < 4; l++) {
    wconv_k<<<dim3(3 * DMODEL / 32, DMODEL / 32), 256, 0, stream>>>(
        qkv_w + (size_t)l * DMODEL * 3 * DMODEL, qkvT, DMODEL, 3 * DMODEL);
    wconv_k<<<dim3(DMODEL / 32, DMODEL / 32), 256, 0, stream>>>(
        proj_w + (size_t)l * DMODEL * DMODEL, projT, DMODEL, DMODEL);
    wconv_k<<<dim3(FDIM / 32, DMODEL / 32), 256, 0, stream>>>(
        fc1_w + (size_t)l * DMODEL * FDIM, fc1T, DMODEL, FDIM);
    wconv_k<<<dim3(DMODEL / 32, FDIM / 32), 256, 0, stream>>>(
        fc2_w + (size_t)l * FDIM * DMODEL, fc2T, FDIM, DMODEL);

    ln_k<<<dim3(N), 320, 0, stream>>>(x, h, ln1_s + l * DMODEL, ln1_b + l * DMODEL);
    // qkv (480 blocks, no split)
    gemm(stream, 1, h, qkvT, qkv_b + (size_t)l * 3 * DMODEL, qkvb, N, 3 * DMODEL,
         DMODEL, DMODEL, DMODEL, 3 * DMODEL, 1.f, 0, 0, 0, 1, 1);
    rope_k<<<dim3(N, NHEADS), 64, 0, stream>>>(qkvb, rw, cl, qr, kr, vp, N);
    // scores = iscale * Q.K^T per (head,seg)  (1024 blocks)
    gemm(stream, 2, qr, kr, nullptr, bigA, SEG, SEG, 96, 96, 96, SEG, iscale,
         (long long)SEG * 96, (long long)SEG * 96, (long long)SEG * SEG, nb, 1);
    softmax_k<<<dim3(SEG, nb), 64, 0, stream>>>(bigA, P);
    vtr_k<<<dim3(8, 2, nb), 256, 0, stream>>>(vp, vpT);
    // O = P.V split-K=2 (512 blocks), bf16 partials
    gemm(stream, 0, P, vpT, nullptr, op, SEG, 128, SEG, SEG, SEG, 128, 1.f,
         (long long)SEG * SEG, (long long)128 * SEG, (long long)2 * SEG * 128, nb, 2);
    repack_k<<<dim3((N * DMODEL + 255) / 256), 256, 0, stream>>>(op, o, N);
    // proj split-K=4 (640 blocks) + bias + residual
    gemm(stream, 0, o, projT, nullptr, part, N, DMODEL, DMODEL, DMODEL, DMODEL,
         DMODEL, 1.f, 0, 0, 0, 1, 4);
    reduce_k<4, 1, 0, 0><<<dim3((int)(((long long)N * DMODEL / 4 + 255) / 256)), 256, 0, stream>>>(
        part, (long long)N * DMODEL, DMODEL, proj_b + (size_t)l * DMODEL, x, x);
    ln_k<<<dim3(N), 320, 0, stream>>>(x, h, ln2_s + l * DMODEL, ln2_b + l * DMODEL);
    // fc1 fused bias+gelu -> bf16 (640 blocks)
    gemm(stream, 3, h, fc1T, fc1_b + (size_t)l * FDIM, ffb, N, FDIM, DMODEL,
         DMODEL, DMODEL, FDIM, 1.f, 0, 0, 0, 1, 1);
    // fc2 split-K=4 (640 blocks) + bias + residual
    gemm(stream, 0, ffb, fc2T, nullptr, part, N, DMODEL, FDIM, FDIM, FDIM,
         DMODEL, 1.f, 0, 0, 0, 1, 4);
    reduce_k<4, 1, 0, 0><<<dim3((int)(((long long)N * DMODEL / 4 + 255) / 256)), 256, 0, stream>>>(
        part, (long long)N * DMODEL, DMODEL, fc2_b + (size_t)l * DMODEL, x, x);
  }

  // merger
  ln_k<<<dim3(N), 320, 0, stream>>>(x, h, mns, mnb);  // h viewed as [512][5120]
  const int Mm = N / 4;  // 512
  wconv_k<<<dim3(FDIM / 32, FDIM / 32), 256, 0, stream>>>(mf1w, mfc1T, FDIM, FDIM);
  // mfc1 split-K=4 (640 blocks)
  gemm(stream, 0, h, mfc1T, nullptr, part, Mm, FDIM, FDIM, FDIM, FDIM, FDIM,
       1.f, 0, 0, 0, 1, 4);
  reduce_k<4, 0, 1, 1><<<dim3((int)(((long long)Mm * FDIM / 4 + 255) / 256)), 256, 0, stream>>>(
      part, (long long)Mm * FDIM, FDIM, mf1b, nullptr, mf);
  wconv_k<<<dim3(2048 / 32, FDIM / 32), 256, 0, stream>>>(mf2w, mfc2T, FDIM, 2048);
  // mfc2 split-K=8 (512 blocks)
  gemm(stream, 0, mf, mfc2T, nullptr, part, Mm, 2048, FDIM, FDIM, FDIM, 2048,
       1.f, 0, 0, 0, 1, 8);
  reduce_k<8, 0, 0, 0><<<dim3((int)(((long long)Mm * 2048 / 4 + 255) / 256)), 256, 0, stream>>>(
      part, (long long)Mm * 2048, 2048, mf2b, nullptr, out);
}